// Round 4
// baseline (280.848 us; speedup 1.0000x reference)
//
#include <hip/hip_runtime.h>

// Problem constants (from reference)
constexpr int N_CONTEXT = 9;
constexpr int C      = 26;                  // N_INPUT
constexpr int WINDOW = 2 * N_CONTEXT + 1;   // 19
constexpr int BATCH  = 64;
constexpr int TIME   = 2000;
constexpr int ROW    = WINDOW * C;          // 494 floats per output row

// out[r*494 + j] = x[(r-9)*26 + j] masked by 0 <= (r%2000) + j/26 - 9 < 2000:
// a shifted streaming copy. Grid-stride chosen so stride*4 is a multiple of
// 494 -> j / w / straddle are LOOP-INVARIANT (magic divs hoisted).
constexpr long long OUT_FLOATS = (long long)BATCH * TIME * ROW; // 63,232,000
constexpr int OUT_VEC4   = (int)(OUT_FLOATS / 4);               // 15,808,000
constexpr int BLOCK      = 256;
constexpr int ITERS      = 5;
constexpr int GRID       = OUT_VEC4 / (BLOCK * ITERS);          // 12,350 exact
constexpr int STRIDE_V4  = GRID * BLOCK;                        // 3,161,600
constexpr int R_STEP     = STRIDE_V4 * 4 / ROW;                 // 25,600 exact (494*25600 = 12,646,400)
constexpr int T_STEP     = R_STEP % TIME;                       // 1,600
constexpr int SRC_STEP   = STRIDE_V4 * 4 - 468 * R_STEP;        // 665,600

typedef float vfloat4 __attribute__((ext_vector_type(4)));

__global__ __launch_bounds__(BLOCK)
void CreateOverlappingWindows_84963043050043_kernel(const float* __restrict__ x,
                                                    float* __restrict__ out) {
    const int tid = blockIdx.x * BLOCK + threadIdx.x;   // vec4 index, iter 0
    const int F   = tid * 4;                            // float index, iter 0
    const int r   = F / ROW;                            // magic div (hoisted)
    const int j   = F - r * ROW;                        // even, 0..492, loop-invariant
    int       t   = r % TIME;                           // magic div (hoisted)
    const int w0  = j / C;                              // magic div (hoisted)
    const int m   = j - w0 * C;                         // j % 26
    const bool straddle = (j == ROW - 2);               // vec4 spans rows r, r+1
    // pair1 = elements 2,3: same row unless straddle (then row r+1, w=0).
    const int w1   = straddle ? 0 : ((m == C - 2) ? w0 + 1 : w0);
    const int dt1  = straddle ? 1 : 0;                  // pair1 time offset
    const int off1 = straddle ? (2 - (ROW - C)) : 2;    // pair1 src offset (-466 or +2)
    int       src  = F - (ROW - C) * r - N_CONTEXT * C; // = (r-9)*26 + j; 8B-aligned

    #pragma unroll
    for (int i = 0; i < ITERS; ++i) {
        const int st0 = t + w0 - N_CONTEXT;             // pair0 source time
        int t1 = t + dt1; if (t1 == TIME) t1 = 0;       // batch wrap -> masked below
        const int st1 = t1 + w1 - N_CONTEXT;            // pair1 source time

        float2 p0 = make_float2(0.0f, 0.0f);
        float2 p1 = make_float2(0.0f, 0.0f);
        if ((unsigned)st0 < (unsigned)TIME)
            p0 = *reinterpret_cast<const float2*>(x + src);
        if ((unsigned)st1 < (unsigned)TIME)
            p1 = *reinterpret_cast<const float2*>(x + src + off1);

        vfloat4 v; v.x = p0.x; v.y = p0.y; v.z = p1.x; v.w = p1.y;
        __builtin_nontemporal_store(
            v, reinterpret_cast<vfloat4*>(out) + tid + i * STRIDE_V4);

        t += T_STEP; if (t >= TIME) t -= TIME;
        src += SRC_STEP;
    }
}

extern "C" void kernel_launch(void* const* d_in, const int* in_sizes, int n_in,
                              void* d_out, int out_size, void* d_ws, size_t ws_size,
                              hipStream_t stream) {
    const float* x = (const float*)d_in[0];
    float* out = (float*)d_out;
    CreateOverlappingWindows_84963043050043_kernel<<<GRID, BLOCK, 0, stream>>>(x, out);
}

// Round 5
// 252.795 us; speedup vs baseline: 1.1110x; 1.1110x over previous
//
#include <hip/hip_runtime.h>

// Problem constants (from reference)
constexpr int N_CONTEXT = 9;
constexpr int C         = 26;                 // N_INPUT
constexpr int WINDOW    = 2 * N_CONTEXT + 1;  // 19
constexpr int BATCH     = 64;
constexpr int TIME      = 2000;
constexpr int ROW       = WINDOW * C;         // 494 floats per output row

// Tiling: one block handles T_TILE consecutive output rows (same batch).
constexpr int T_TILE      = 16;                   // 16 | 2000 -> tiles never cross batch
constexpr int LDS_ROWS    = T_TILE + WINDOW - 1;  // 34 time steps staged
constexpr int LDS_FLOATS  = LDS_ROWS * C;         // 884
constexpr int TILE_FLOATS = T_TILE * ROW;         // 7904
constexpr int TILE_VEC4   = TILE_FLOATS / 4;      // 1976 (r0 even -> 16B aligned)
constexpr int BLOCK       = 256;
constexpr int NBLOCKS     = BATCH * TIME / T_TILE; // 8000
constexpr int BATCH_FLOATS = TIME * C;             // 52000

typedef float vfloat4 __attribute__((ext_vector_type(4)));

__global__ __launch_bounds__(BLOCK)
void CreateOverlappingWindows_84963043050043_kernel(const float* __restrict__ x,
                                                    float* __restrict__ out) {
    __shared__ float lds[LDS_FLOATS];
    const int blk = blockIdx.x;
    const int tid = threadIdx.x;
    const int r0  = blk * T_TILE;          // first output row of tile (even)
    const int b   = r0 / TIME;             // batch index (tile is batch-uniform)
    const int lo  = b * BATCH_FLOATS;      // valid flat-index range for this batch
    const int g0  = (r0 - N_CONTEXT) * C;  // may be negative at t=0 edge

    // Phase 1: stage x[b, t0-9 .. t0+T_TILE+8, :] into LDS, zeros materialized
    // for out-of-range times (validity == flat index within batch range).
    #pragma unroll
    for (int it = 0; it < (LDS_FLOATS + BLOCK - 1) / BLOCK; ++it) {
        int idx = tid + it * BLOCK;
        if (idx < LDS_FLOATS) {
            int g = g0 + idx;
            lds[idx] = ((unsigned)(g - lo) < (unsigned)BATCH_FLOATS) ? x[g] : 0.0f;
        }
    }
    __syncthreads();

    // Phase 2: each output row is a CONTIGUOUS 494-float LDS window starting
    // at lt*26 (out elem (lt, j=w*26+c) <- src (lt+w)*26+c = lds[lt*26+j]).
    // a is always even -> read as two float2 (ds_read_b64): 16 banks touched
    // instead of 8, half the instructions vs 4x ds_read_b32 (R3's 8-way
    // conflict). Only straddle within a vec4 is j==492 (elements 2,3 wrap to
    // row lt+1 at address -468), branchless via 'sub'.
    const float2* lds2 = reinterpret_cast<const float2*>(lds);
    vfloat4* out4 = reinterpret_cast<vfloat4*>(out) + (size_t)blk * TILE_VEC4;
    #pragma unroll
    for (int it = 0; it < (TILE_VEC4 + BLOCK - 1) / BLOCK; ++it) {
        int q = tid + it * BLOCK;
        if (q < TILE_VEC4) {
            int f  = q * 4;                 // float index within tile
            int lt = f / ROW;               // local row 0..15 (magic-mul)
            int j  = f - lt * ROW;          // even, 0..492
            int a  = lt * C + j;            // LDS window address (even)
            int sub = (j == ROW - 2) ? (ROW - C) : 0;   // 492 -> -468 (even)
            float2 p0 = lds2[a >> 1];
            float2 p1 = lds2[(a + 2 - sub) >> 1];
            vfloat4 v; v.x = p0.x; v.y = p0.y; v.z = p1.x; v.w = p1.y;
            out4[q] = v;                    // plain store (no nt) — A/B vs R3
        }
    }
}

extern "C" void kernel_launch(void* const* d_in, const int* in_sizes, int n_in,
                              void* d_out, int out_size, void* d_ws, size_t ws_size,
                              hipStream_t stream) {
    const float* x = (const float*)d_in[0];
    float* out = (float*)d_out;
    CreateOverlappingWindows_84963043050043_kernel<<<NBLOCKS, BLOCK, 0, stream>>>(x, out);
}